// Round 5
// baseline (500.239 us; speedup 1.0000x reference)
//
#include <hip/hip_runtime.h>

#define EPS 1e-5f

// native vector type (accepted by __builtin_nontemporal_store)
typedef float nfloat4 __attribute__((ext_vector_type(4)));

// B=8, T=8192, C=512 fixed by setup_inputs().
//
// Single kernel, 1024 blocks x 256 threads, cooperative launch for guaranteed
// co-residency (4 blocks/CU via __launch_bounds__(256,4)); cg::grid.sync()
// measured ~130us each on this chip (R3), so we use a custom lightweight
// barrier: device-scope release atomicAdd arrival + acquire spin.
// Phase 1: block stages stats for its 64 frames -> ws.
// Phase 2: blocks 0..7 scan one batch row each (4 chunks x 2048 frames).
// Phase 3: each block normalizes the same 64 frames it staged (x re-read is
// L2/L3-warm; out is write-only -> nontemporal store).
__global__ __launch_bounds__(256, 4) void cgn_fused2(
    const float* __restrict__ x, const float* __restrict__ w,
    float* __restrict__ out, float* __restrict__ ws,
    unsigned int* __restrict__ flags) {
  const int T = 8192;
  const int BT = 65536;
  float* s_arr = ws;
  float* q_arr = ws + BT;
  float* mean_arr = ws + 2 * BT;
  float* inv_arr = ws + 3 * BT;

  __shared__ float lds_s[4];
  __shared__ float lds_v[4];

  const int tid = threadIdx.x;
  const int lane = tid & 63;
  const int wid = tid >> 6;
  const int f0 = blockIdx.x * 64 + wid * 16;
  const nfloat4* x4 = (const nfloat4*)x;

  // ---------------- Phase 1: frame stats ----------------
#pragma unroll 4
  for (int f = 0; f < 16; ++f) {
    const int frame = f0 + f;
    const nfloat4* fb = x4 + (size_t)frame * 128;  // 128 float4 per frame
    nfloat4 a = fb[lane];
    nfloat4 b = fb[64 + lane];
    float s = a.x + a.y + a.z + a.w + b.x + b.y + b.z + b.w;
    float q = a.x * a.x + a.y * a.y + a.z * a.z + a.w * a.w +
              b.x * b.x + b.y * b.y + b.z * b.z + b.w * b.w;
#pragma unroll
    for (int off = 32; off >= 1; off >>= 1) {
      s += __shfl_down(s, off);
      q += __shfl_down(q, off);
    }
    if (lane == 0) {
      s_arr[frame] = s;
      q_arr[frame] = q;
    }
  }
  __syncthreads();
  __threadfence();  // publish phase-1 stores (agent scope)
  if (tid == 0)
    __hip_atomic_fetch_add(&flags[0], 1u, __ATOMIC_RELEASE,
                           __HIP_MEMORY_SCOPE_AGENT);

  // ---------------- Phase 2: per-batch coupled scans (blocks 0..7) --------
  if (blockIdx.x < 8) {
    if (tid == 0) {
      while (__hip_atomic_load(&flags[0], __ATOMIC_ACQUIRE,
                               __HIP_MEMORY_SCOPE_AGENT) < 1024u)
        __builtin_amdgcn_s_sleep(1);
    }
    __syncthreads();

    const int b = blockIdx.x;
    const nfloat4* s4p = (const nfloat4*)(s_arr + (size_t)b * T);
    const nfloat4* q4p = (const nfloat4*)(q_arr + (size_t)b * T);
    nfloat4* m4p = (nfloat4*)(mean_arr + (size_t)b * T);
    nfloat4* i4p = (nfloat4*)(inv_arr + (size_t)b * T);
    float carryS = 0.f, carryV = 0.f;
#pragma unroll 1
    for (int c = 0; c < 4; ++c) {          // chunks of 2048 frames
      const int idx4 = (c << 9) + 2 * tid; // 512 float4 per chunk
      nfloat4 sa = s4p[idx4];
      nfloat4 sb = s4p[idx4 + 1];
      nfloat4 qa = q4p[idx4];
      nfloat4 qb = q4p[idx4 + 1];

      // per-thread prefix of 8, wave scan, cross-wave via LDS
      float p0 = sa.x;
      float p1 = p0 + sa.y;
      float p2 = p1 + sa.z;
      float p3 = p2 + sa.w;
      float p4 = p3 + sb.x;
      float p5 = p4 + sb.y;
      float p6 = p5 + sb.z;
      float p7 = p6 + sb.w;
      float tot = p7, incl = tot;
#pragma unroll
      for (int off = 1; off < 64; off <<= 1) {
        float n = __shfl_up(incl, off);
        if (lane >= off) incl += n;
      }
      if (lane == 63) lds_s[wid] = incl;
      __syncthreads();
      float waveExclS = 0.f, chunkTotS = 0.f;
#pragma unroll
      for (int wv = 0; wv < 4; ++wv) {
        float tv = lds_s[wv];
        if (wv < wid) waveExclS += tv;
        chunkTotS += tv;
      }
      float base = carryS + waveExclS + (incl - tot);
      carryS += chunkTotS;

      const int t0 = (c << 11) + (tid << 3);  // frame index within batch
      float c0 = (float)(t0 + 1) * 512.f;
      float c1 = (float)(t0 + 2) * 512.f;
      float c2 = (float)(t0 + 3) * 512.f;
      float c3 = (float)(t0 + 4) * 512.f;
      float c4 = (float)(t0 + 5) * 512.f;
      float c5 = (float)(t0 + 6) * 512.f;
      float c6 = (float)(t0 + 7) * 512.f;
      float c7 = (float)(t0 + 8) * 512.f;
      float m0 = (base + p0) / c0;
      float m1 = (base + p1) / c1;
      float m2 = (base + p2) / c2;
      float m3 = (base + p3) / c3;
      float m4 = (base + p4) / c4;
      float m5 = (base + p5) / c5;
      float m6 = (base + p6) / c6;
      float m7 = (base + p7) / c7;

      // per-frame squared-deviation sum: q - 2*m*s + C*m^2
      float v0 = qa.x - 2.f * m0 * sa.x + 512.f * m0 * m0;
      float v1 = qa.y - 2.f * m1 * sa.y + 512.f * m1 * m1;
      float v2 = qa.z - 2.f * m2 * sa.z + 512.f * m2 * m2;
      float v3 = qa.w - 2.f * m3 * sa.w + 512.f * m3 * m3;
      float v4 = qb.x - 2.f * m4 * sb.x + 512.f * m4 * m4;
      float v5 = qb.y - 2.f * m5 * sb.y + 512.f * m5 * m5;
      float v6 = qb.z - 2.f * m6 * sb.z + 512.f * m6 * m6;
      float v7 = qb.w - 2.f * m7 * sb.w + 512.f * m7 * m7;

      float r0 = v0;
      float r1 = r0 + v1;
      float r2 = r1 + v2;
      float r3 = r2 + v3;
      float r4 = r3 + v4;
      float r5 = r4 + v5;
      float r6 = r5 + v6;
      float r7 = r6 + v7;
      float totv = r7, inclv = totv;
#pragma unroll
      for (int off = 1; off < 64; off <<= 1) {
        float n = __shfl_up(inclv, off);
        if (lane >= off) inclv += n;
      }
      if (lane == 63) lds_v[wid] = inclv;
      __syncthreads();
      float waveExclV = 0.f, chunkTotV = 0.f;
#pragma unroll
      for (int wv = 0; wv < 4; ++wv) {
        float tv = lds_v[wv];
        if (wv < wid) waveExclV += tv;
        chunkTotV += tv;
      }
      float baseV = carryV + waveExclV + (inclv - totv);
      carryV += chunkTotV;

      nfloat4 moa, mob, ioa, iob;
      moa.x = m0; moa.y = m1; moa.z = m2; moa.w = m3;
      mob.x = m4; mob.y = m5; mob.z = m6; mob.w = m7;
      ioa.x = rsqrtf((baseV + r0) / c0 + EPS);
      ioa.y = rsqrtf((baseV + r1) / c1 + EPS);
      ioa.z = rsqrtf((baseV + r2) / c2 + EPS);
      ioa.w = rsqrtf((baseV + r3) / c3 + EPS);
      iob.x = rsqrtf((baseV + r4) / c4 + EPS);
      iob.y = rsqrtf((baseV + r5) / c5 + EPS);
      iob.z = rsqrtf((baseV + r6) / c6 + EPS);
      iob.w = rsqrtf((baseV + r7) / c7 + EPS);
      m4p[idx4] = moa;
      m4p[idx4 + 1] = mob;
      i4p[idx4] = ioa;
      i4p[idx4 + 1] = iob;
    }

    __syncthreads();
    __threadfence();
    if (tid == 0)
      __hip_atomic_fetch_add(&flags[1], 1u, __ATOMIC_RELEASE,
                             __HIP_MEMORY_SCOPE_AGENT);
  }

  // ---------------- barrier: wait for all 8 scans ----------------
  if (tid == 0) {
    while (__hip_atomic_load(&flags[1], __ATOMIC_ACQUIRE,
                             __HIP_MEMORY_SCOPE_AGENT) < 8u)
      __builtin_amdgcn_s_sleep(1);
  }
  __syncthreads();

  // ---------------- Phase 3: apply ----------------
  const nfloat4 wa = ((const nfloat4*)w)[lane];
  const nfloat4 wb = ((const nfloat4*)w)[64 + lane];
  nfloat4* out4 = (nfloat4*)out;
#pragma unroll 4
  for (int f = 0; f < 16; ++f) {
    const int frame = f0 + f;
    const float m = mean_arr[frame];
    const float iv = inv_arr[frame];
    const nfloat4* fb = x4 + (size_t)frame * 128;
    nfloat4 a = fb[lane];
    nfloat4 b = fb[64 + lane];
    nfloat4 oa, ob;
    oa.x = (a.x - m) * iv * wa.x;
    oa.y = (a.y - m) * iv * wa.y;
    oa.z = (a.z - m) * iv * wa.z;
    oa.w = (a.w - m) * iv * wa.w;
    ob.x = (b.x - m) * iv * wb.x;
    ob.y = (b.y - m) * iv * wb.y;
    ob.z = (b.z - m) * iv * wb.z;
    ob.w = (b.w - m) * iv * wb.w;
    __builtin_nontemporal_store(oa, out4 + (size_t)frame * 128 + lane);
    __builtin_nontemporal_store(ob, out4 + (size_t)frame * 128 + 64 + lane);
  }
}

extern "C" void kernel_launch(void* const* d_in, const int* in_sizes, int n_in,
                              void* d_out, int out_size, void* d_ws,
                              size_t ws_size, hipStream_t stream) {
  const float* x = (const float*)d_in[0];
  const float* w = (const float*)d_in[1];
  float* out = (float*)d_out;
  const int BT = 65536;

  float* ws = (float*)d_ws;                          // 4*BT floats = 1 MiB
  unsigned int* flags = (unsigned int*)(ws + 4 * BT);

  // d_ws is poisoned 0xAA before every timed launch -> zero the flags.
  (void)hipMemsetAsync(flags, 0, 2 * sizeof(unsigned int), stream);

  void* kargs[] = {(void*)&x, (void*)&w, (void*)&out, (void*)&ws,
                   (void*)&flags};
  (void)hipLaunchCooperativeKernel((const void*)cgn_fused2, dim3(1024),
                                   dim3(256), kargs, 0, stream);
}

// Round 6
// 247.914 us; speedup vs baseline: 2.0178x; 2.0178x over previous
//
#include <hip/hip_runtime.h>

#define EPS 1e-5f

// native vector type (accepted by __builtin_nontemporal_store)
typedef float nfloat4 __attribute__((ext_vector_type(4)));

// B=8, T=8192, C=512 fixed by setup_inputs().

// K1: per-frame channel sum + sumsq. One wave per frame (C=512 -> 2 float4
// per lane), shuffle reduce. Pure HBM-read bound (128 MiB).
__global__ __launch_bounds__(256) void frame_stats_kernel(
    const float* __restrict__ x, float* __restrict__ s_arr,
    float* __restrict__ q_arr) {
  const int wave = threadIdx.x >> 6;
  const int lane = threadIdx.x & 63;
  const int frame = blockIdx.x * 4 + wave;
  const nfloat4* xb = (const nfloat4*)(x + (size_t)frame * 512);
  nfloat4 a = xb[lane];       // floats [0,256)
  nfloat4 b = xb[64 + lane];  // floats [256,512)
  float s = a.x + a.y + a.z + a.w + b.x + b.y + b.z + b.w;
  float q = a.x * a.x + a.y * a.y + a.z * a.z + a.w * a.w +
            b.x * b.x + b.y * b.y + b.z * b.z + b.w * b.w;
#pragma unroll
  for (int off = 32; off >= 1; off >>= 1) {
    s += __shfl_down(s, off);
    q += __shfl_down(q, off);
  }
  if (lane == 0) {
    s_arr[frame] = s;
    q_arr[frame] = q;
  }
}

// K3': scan + apply fused, NO cross-block sync. 512 blocks x 1024 threads;
// 64 blocks per batch row, each redundantly computes the full row scan
// (one pass: per-thread prefix of 8 frames, wave scan, 16-wave LDS combine
// -- ~64 KiB of stats from L2/L3, ~3us), keeps mean/inv for its own
// 128-frame slice in LDS, then streams the normalize for that slice
// (x re-read is L3-warm from K1; out is write-only -> nontemporal store).
__global__ __launch_bounds__(1024) void scan_apply_kernel(
    const float* __restrict__ x, const float* __restrict__ w,
    const float* __restrict__ s_arr, const float* __restrict__ q_arr,
    float* __restrict__ out) {
  const int T = 8192;
  const int tid = threadIdx.x;
  const int lane = tid & 63;
  const int wid = tid >> 6;  // 16 waves
  const int b = blockIdx.x >> 6;          // batch row
  const int slice = blockIdx.x & 63;      // 128-frame slice within row

  __shared__ float lds_s[16];
  __shared__ float lds_v[16];
  __shared__ float lds_m[128];
  __shared__ float lds_i[128];

  // ---------------- full-row coupled scan (redundant per block) ----------
  const nfloat4* s4p = (const nfloat4*)(s_arr + (size_t)b * T);
  const nfloat4* q4p = (const nfloat4*)(q_arr + (size_t)b * T);

  nfloat4 sa = s4p[2 * tid];
  nfloat4 sb = s4p[2 * tid + 1];
  nfloat4 qa = q4p[2 * tid];
  nfloat4 qb = q4p[2 * tid + 1];

  // scan of s
  float p0 = sa.x;
  float p1 = p0 + sa.y;
  float p2 = p1 + sa.z;
  float p3 = p2 + sa.w;
  float p4 = p3 + sb.x;
  float p5 = p4 + sb.y;
  float p6 = p5 + sb.z;
  float p7 = p6 + sb.w;
  float tot = p7, incl = tot;
#pragma unroll
  for (int off = 1; off < 64; off <<= 1) {
    float n = __shfl_up(incl, off);
    if (lane >= off) incl += n;
  }
  if (lane == 63) lds_s[wid] = incl;
  __syncthreads();
  float waveExcl = 0.f;
#pragma unroll
  for (int wv = 0; wv < 16; ++wv)
    if (wv < wid) waveExcl += lds_s[wv];
  float base = waveExcl + incl - tot;

  const int t0 = tid << 3;  // first frame owned by this thread
  float c0 = (float)(t0 + 1) * 512.f;
  float c1 = (float)(t0 + 2) * 512.f;
  float c2 = (float)(t0 + 3) * 512.f;
  float c3 = (float)(t0 + 4) * 512.f;
  float c4 = (float)(t0 + 5) * 512.f;
  float c5 = (float)(t0 + 6) * 512.f;
  float c6 = (float)(t0 + 7) * 512.f;
  float c7 = (float)(t0 + 8) * 512.f;
  float m0 = (base + p0) / c0;
  float m1 = (base + p1) / c1;
  float m2 = (base + p2) / c2;
  float m3 = (base + p3) / c3;
  float m4 = (base + p4) / c4;
  float m5 = (base + p5) / c5;
  float m6 = (base + p6) / c6;
  float m7 = (base + p7) / c7;

  // per-frame squared-deviation sum: q - 2*m*s + C*m^2
  float v0 = qa.x - 2.f * m0 * sa.x + 512.f * m0 * m0;
  float v1 = qa.y - 2.f * m1 * sa.y + 512.f * m1 * m1;
  float v2 = qa.z - 2.f * m2 * sa.z + 512.f * m2 * m2;
  float v3 = qa.w - 2.f * m3 * sa.w + 512.f * m3 * m3;
  float v4 = qb.x - 2.f * m4 * sb.x + 512.f * m4 * m4;
  float v5 = qb.y - 2.f * m5 * sb.y + 512.f * m5 * m5;
  float v6 = qb.z - 2.f * m6 * sb.z + 512.f * m6 * m6;
  float v7 = qb.w - 2.f * m7 * sb.w + 512.f * m7 * m7;

  // scan of v
  float r0 = v0;
  float r1 = r0 + v1;
  float r2 = r1 + v2;
  float r3 = r2 + v3;
  float r4 = r3 + v4;
  float r5 = r4 + v5;
  float r6 = r5 + v6;
  float r7 = r6 + v7;
  float totv = r7, inclv = totv;
#pragma unroll
  for (int off = 1; off < 64; off <<= 1) {
    float n = __shfl_up(inclv, off);
    if (lane >= off) inclv += n;
  }
  if (lane == 63) lds_v[wid] = inclv;
  __syncthreads();
  float waveExclV = 0.f;
#pragma unroll
  for (int wv = 0; wv < 16; ++wv)
    if (wv < wid) waveExclV += lds_v[wv];
  float baseV = waveExclV + inclv - totv;

  // stash mean/inv for this block's 128-frame slice into LDS.
  // thread t owns frames [8t, 8t+8); slice covers frames [slice*128, +128),
  // i.e. threads [slice*16, slice*16+16).
  const int sliceFirstThread = slice << 4;
  if ((tid >> 4) == slice) {
    const int k = (tid - sliceFirstThread) << 3;  // 0..127, step 8
    lds_m[k + 0] = m0;
    lds_m[k + 1] = m1;
    lds_m[k + 2] = m2;
    lds_m[k + 3] = m3;
    lds_m[k + 4] = m4;
    lds_m[k + 5] = m5;
    lds_m[k + 6] = m6;
    lds_m[k + 7] = m7;
    lds_i[k + 0] = rsqrtf((baseV + r0) / c0 + EPS);
    lds_i[k + 1] = rsqrtf((baseV + r1) / c1 + EPS);
    lds_i[k + 2] = rsqrtf((baseV + r2) / c2 + EPS);
    lds_i[k + 3] = rsqrtf((baseV + r3) / c3 + EPS);
    lds_i[k + 4] = rsqrtf((baseV + r4) / c4 + EPS);
    lds_i[k + 5] = rsqrtf((baseV + r5) / c5 + EPS);
    lds_i[k + 6] = rsqrtf((baseV + r6) / c6 + EPS);
    lds_i[k + 7] = rsqrtf((baseV + r7) / c7 + EPS);
  }
  __syncthreads();

  // ---------------- apply for this slice ----------------
  // slice = frames [b*8192 + slice*128, +128) -> float4 index range
  // [base4, base4 + 16384). Thread handles 16 float4, stride 1024.
  // c4 = (k*1024 + tid) & 127 = tid & 127 (constant) -> load w once.
  const size_t base4 = ((size_t)b * 8192 + (size_t)slice * 128) * 128;
  const nfloat4 wv4 = ((const nfloat4*)w)[tid & 127];
  const nfloat4* x4 = (const nfloat4*)x;
  nfloat4* out4 = (nfloat4*)out;
#pragma unroll 4
  for (int k = 0; k < 16; ++k) {
    const size_t idx = base4 + (size_t)(k << 10) + tid;
    const int frame_local = (int)((idx >> 7) & 127) ;
    // frame_local within slice: ((k*1024+tid)>>7) = k*8 + (tid>>7)
    nfloat4 xv = x4[idx];
    const float m = lds_m[(k << 3) + (tid >> 7)];
    const float iv = lds_i[(k << 3) + (tid >> 7)];
    (void)frame_local;
    nfloat4 o;
    o.x = (xv.x - m) * iv * wv4.x;
    o.y = (xv.y - m) * iv * wv4.y;
    o.z = (xv.z - m) * iv * wv4.z;
    o.w = (xv.w - m) * iv * wv4.w;
    __builtin_nontemporal_store(o, out4 + idx);
  }
}

extern "C" void kernel_launch(void* const* d_in, const int* in_sizes, int n_in,
                              void* d_out, int out_size, void* d_ws,
                              size_t ws_size, hipStream_t stream) {
  const float* x = (const float*)d_in[0];
  const float* w = (const float*)d_in[1];
  float* out = (float*)d_out;
  const int BT = 65536;

  float* s_arr = (float*)d_ws;  // BT floats
  float* q_arr = s_arr + BT;    // BT floats

  frame_stats_kernel<<<BT / 4, 256, 0, stream>>>(x, s_arr, q_arr);
  scan_apply_kernel<<<512, 1024, 0, stream>>>(x, w, s_arr, q_arr, out);
}